// Round 2
// baseline (148.819 us; speedup 1.0000x reference)
//
#include <hip/hip_runtime.h>
#include <hip/hip_bf16.h>
#include <cstdint>

// TT-linear: y[4096,4096] = x[4096,1024] @ W[1024,4096] + bias
// Kernel 1 (prep): fused x->bf16 convert + W^T reconstruction from TT cores (unchanged).
// Kernel 2 (tt_gemm): 256x256 tile, 8 waves, BK=32, 4-deep LDS pipeline.
// Round-2 fix: raw __builtin_amdgcn_s_barrier() + CLOBBERLESS counted vmcnt asm,
// pinned with sched_barrier(0). Round-1 used "memory"-clobbered asm, which forced
// the backend to insert s_waitcnt vmcnt(0) before every barrier/waitcnt (drain),
// killing the counted pipeline (observed: identical 60us, MfmaUtil 21%).

typedef __bf16 bf16x8 __attribute__((ext_vector_type(8)));
typedef float f32x4 __attribute__((ext_vector_type(4)));

__device__ __forceinline__ void g2lds16(const void* g, void* l) {
    __builtin_amdgcn_global_load_lds(
        (const __attribute__((address_space(1))) void*)g,
        (__attribute__((address_space(3))) void*)l,
        16, 0, 0);
}

// --------------------------------------------------------------------- prep
__global__ __launch_bounds__(256) void prep(
    const float* __restrict__ x, __bf16* __restrict__ xb,
    const float* __restrict__ c0, const float* __restrict__ c1,
    const float* __restrict__ c2, const float* __restrict__ c3,
    __bf16* __restrict__ wt) {
    const int b = blockIdx.x;
    const int t = threadIdx.x;
    if (b < 2048) {
        const int i = (b * 256 + t) * 8;
        float4 a0 = *(const float4*)(x + i);
        float4 a1 = *(const float4*)(x + i + 4);
        bf16x8 o;
        o[0] = (__bf16)a0.x; o[1] = (__bf16)a0.y; o[2] = (__bf16)a0.z; o[3] = (__bf16)a0.w;
        o[4] = (__bf16)a1.x; o[5] = (__bf16)a1.y; o[6] = (__bf16)a1.z; o[7] = (__bf16)a1.w;
        *(bf16x8*)(xb + i) = o;
        return;
    }
    __shared__ float t12[4][16];     // [wave][r2]
    __shared__ float t123[4][512];   // [wave][m3*8+n3][r3]
    __shared__ float c3s[512];       // [(r3*4+m4)*8+n4]
    #pragma unroll
    for (int i = t; i < 512; i += 256) c3s[i] = c3[i];
    const int s = t >> 6;
    const int lane = t & 63;
    const int g = (b - 2048) * 4 + s;
    const int m1 = g >> 9, n1 = (g >> 6) & 7, m2 = (g >> 3) & 7, n2 = g & 7;
    __syncthreads();
    if (lane < 16) {
        const int r2 = lane;
        float sum = 0.f;
        #pragma unroll
        for (int r1 = 0; r1 < 16; ++r1)
            sum += c0[(m1 * 8 + n1) * 16 + r1] * c1[((r1 * 8 + m2) * 8 + n2) * 16 + r2];
        t12[s][r2] = sum;
    }
    __syncthreads();
    #pragma unroll
    for (int idx = lane; idx < 512; idx += 64) {
        const int m3 = idx >> 7, n3 = (idx >> 4) & 7, r3 = idx & 15;
        float sum = 0.f;
        #pragma unroll
        for (int r2 = 0; r2 < 16; ++r2)
            sum += t12[s][r2] * c2[((r2 * 4 + m3) * 8 + n3) * 16 + r3];
        t123[s][(m3 * 8 + n3) * 16 + r3] = sum;
    }
    __syncthreads();
    const int n3 = lane >> 3, n4 = lane & 7;
    const int n = ((n1 * 8 + n2) * 8 + n3) * 8 + n4;
    const int kbase = (m1 * 8 + m2) * 16;
    float v[16];
    #pragma unroll
    for (int e = 0; e < 16; ++e) v[e] = 0.f;
    #pragma unroll
    for (int m3 = 0; m3 < 4; ++m3) {
        #pragma unroll
        for (int r3 = 0; r3 < 16; ++r3) {
            const float tv = t123[s][(m3 * 8 + n3) * 16 + r3];
            #pragma unroll
            for (int m4 = 0; m4 < 4; ++m4)
                v[m3 * 4 + m4] += tv * c3s[(r3 * 4 + m4) * 8 + n4];
        }
    }
    bf16x8 lo, hi;
    #pragma unroll
    for (int e = 0; e < 8; ++e) { lo[e] = (__bf16)v[e]; hi[e] = (__bf16)v[8 + e]; }
    *(bf16x8*)(wt + (size_t)n * 1024 + kbase)     = lo;
    *(bf16x8*)(wt + (size_t)n * 1024 + kbase + 8) = hi;
}

// -------------------------------------------------------------- GEMM + bias
// C[4096,4096] f32 = A[4096,1024] bf16 @ Bt[4096,1024]^T bf16 + bias
// 256x256 block tile, BK=32, 8 waves (2M x 4N), per-wave 128x64 output.
// LDS: 4 buffers x (A 16KB + B 16KB) = 128 KB. During tile t's two phases we
// stage tile t+3 (A at P1, B at P2). vmcnt(8) at P2 forces everything except
// the newest 8 loads complete => tile t+1 (staged 2 tiles ago) is ready.
// Buffer b[(t+3)&3] = b[(t-1)&3] is only written after tile t-1's end barrier,
// by which point every wave's ds_reads of it have retired (lgkmcnt before MFMA).
// Swizzle: 64-B rows, 4 x 16B chunks; physical chunk pc holds logical pc^((r>>1)&3)
// => fragment ds_read_b128 lands 2 lanes/bank (free). Staging pre-swizzles the
// GLOBAL source; LDS dest stays linear (global_load_lds requirement).

// Raw barrier (no compiler-forced waitcnt drain) pinned against compile-time
// code motion. Counted waitcnt as CLOBBERLESS asm (a "memory" clobber makes the
// backend insert vmcnt(0) before it -- the round-1 bug).
#define SCHED_FENCE() __builtin_amdgcn_sched_barrier(0)
#define BARRIER() do { SCHED_FENCE(); __builtin_amdgcn_s_barrier(); SCHED_FENCE(); } while (0)
#define VMCNT(n)  do { SCHED_FENCE(); asm volatile("s_waitcnt vmcnt(" #n ")"); SCHED_FENCE(); } while (0)

__global__ __launch_bounds__(512, 2) void tt_gemm(
    const __bf16* __restrict__ A, const __bf16* __restrict__ B,
    const float* __restrict__ bias, float* __restrict__ C) {
    constexpr int K = 1024, N = 4096;
    constexpr int NT = K / 32;              // 32 k-tiles
    __shared__ __bf16 sA[4][256 * 32];      // 4 x 16 KB
    __shared__ __bf16 sB[4][256 * 32];      // 4 x 16 KB
    const int t = threadIdx.x;
    const int lane = t & 63;
    const int wave = t >> 6;                // 0..7
    const int wm = (wave >> 2) * 128;       // 0 / 128
    const int wn = (wave & 3) * 64;         // 0..192
    const int l15 = lane & 15, lh = lane >> 4;
    const int coff = (lh ^ ((l15 >> 1) & 3)) * 16;  // swizzled byte offset in 64-B row

    // XCD-aware mapping: each XCD owns an 8m x 4n rectangle of tiles (bijective)
    const int xcd = blockIdx.x & 7;
    const int lid = blockIdx.x >> 3;        // 0..31
    const int bm = ((xcd >> 2) * 8 + (lid & 7)) * 256;
    const int bn = ((xcd & 3) * 4 + (lid >> 3)) * 256;

    // staging: thread owns chunks c = t and t+512 of each 1024-chunk tile
    const int c0i = t, c1i = t + 512;
    const int r0 = c0i >> 2, r1 = c1i >> 2;             // tile row 0..255
    const int lc0 = (c0i & 3) ^ ((r0 >> 1) & 3);        // logical (global) chunk
    const int lc1 = (c1i & 3) ^ ((r1 >> 1) & 3);
    const __bf16* a0p = A + (size_t)(bm + r0) * K + lc0 * 8;
    const __bf16* a1p = A + (size_t)(bm + r1) * K + lc1 * 8;
    const __bf16* b0p = B + (size_t)(bn + r0) * K + lc0 * 8;
    const __bf16* b1p = B + (size_t)(bn + r1) * K + lc1 * 8;

#define STAGE_A(kt) do { \
    g2lds16(a0p + (kt) * 32, (char*)sA[(kt) & 3] + c0i * 16); \
    g2lds16(a1p + (kt) * 32, (char*)sA[(kt) & 3] + c1i * 16); } while (0)
#define STAGE_B(kt) do { \
    g2lds16(b0p + (kt) * 32, (char*)sB[(kt) & 3] + c0i * 16); \
    g2lds16(b1p + (kt) * 32, (char*)sB[(kt) & 3] + c1i * 16); } while (0)

    f32x4 acc[8][4] = {};

    // prologue: stage tiles 0,1,2 (12 loads); wait until tile 0 (oldest 4) done
    STAGE_A(0); STAGE_B(0);
    STAGE_A(1); STAGE_B(1);
    STAGE_A(2); STAGE_B(2);
    VMCNT(8);
    BARRIER();

    #pragma unroll 1
    for (int kt = 0; kt < NT - 3; ++kt) {
        const char* la = (const char*)sA[kt & 3];
        const char* lb = (const char*)sB[kt & 3];
        bf16x8 af[4], bfr[4];
        // ---- phase 1: read A rows wm..wm+63 + all B frags; stage A of kt+3
        #pragma unroll
        for (int mi = 0; mi < 4; ++mi)
            af[mi] = *(const bf16x8*)(la + (wm + mi * 16 + l15) * 64 + coff);
        #pragma unroll
        for (int ni = 0; ni < 4; ++ni)
            bfr[ni] = *(const bf16x8*)(lb + (wn + ni * 16 + l15) * 64 + coff);
        STAGE_A(kt + 3);
        BARRIER();
        __builtin_amdgcn_s_setprio(1);
        #pragma unroll
        for (int mi = 0; mi < 4; ++mi)
            #pragma unroll
            for (int ni = 0; ni < 4; ++ni)
                acc[mi][ni] = __builtin_amdgcn_mfma_f32_16x16x32_bf16(
                    af[mi], bfr[ni], acc[mi][ni], 0, 0, 0);
        __builtin_amdgcn_s_setprio(0);
        BARRIER();
        // ---- phase 2: read A rows wm+64..wm+127; stage B of kt+3; counted wait
        #pragma unroll
        for (int mi = 0; mi < 4; ++mi)
            af[mi] = *(const bf16x8*)(la + (wm + 64 + mi * 16 + l15) * 64 + coff);
        STAGE_B(kt + 3);
        VMCNT(8);
        BARRIER();
        __builtin_amdgcn_s_setprio(1);
        #pragma unroll
        for (int mi = 0; mi < 4; ++mi)
            #pragma unroll
            for (int ni = 0; ni < 4; ++ni)
                acc[4 + mi][ni] = __builtin_amdgcn_mfma_f32_16x16x32_bf16(
                    af[mi], bfr[ni], acc[4 + mi][ni], 0, 0, 0);
        __builtin_amdgcn_s_setprio(0);
        BARRIER();
    }

    // drain remaining stages (tiles 30,31), then 3 tail tiles (no LDS writes left)
    VMCNT(0);
    BARRIER();
    #pragma unroll
    for (int kt = NT - 3; kt < NT; ++kt) {
        const char* la = (const char*)sA[kt & 3];
        const char* lb = (const char*)sB[kt & 3];
        bf16x8 af[4], bfr[4];
        #pragma unroll
        for (int ni = 0; ni < 4; ++ni)
            bfr[ni] = *(const bf16x8*)(lb + (wn + ni * 16 + l15) * 64 + coff);
        #pragma unroll
        for (int mi = 0; mi < 4; ++mi)
            af[mi] = *(const bf16x8*)(la + (wm + mi * 16 + l15) * 64 + coff);
        #pragma unroll
        for (int mi = 0; mi < 4; ++mi)
            #pragma unroll
            for (int ni = 0; ni < 4; ++ni)
                acc[mi][ni] = __builtin_amdgcn_mfma_f32_16x16x32_bf16(
                    af[mi], bfr[ni], acc[mi][ni], 0, 0, 0);
        #pragma unroll
        for (int mi = 0; mi < 4; ++mi)
            af[mi] = *(const bf16x8*)(la + (wm + 64 + mi * 16 + l15) * 64 + coff);
        #pragma unroll
        for (int mi = 0; mi < 4; ++mi)
            #pragma unroll
            for (int ni = 0; ni < 4; ++ni)
                acc[4 + mi][ni] = __builtin_amdgcn_mfma_f32_16x16x32_bf16(
                    af[mi], bfr[ni], acc[4 + mi][ni], 0, 0, 0);
    }

    // epilogue: C/D layout col=lane&15, row=(lane>>4)*4+reg (m89-verified)
    #pragma unroll
    for (int ni = 0; ni < 4; ++ni) {
        const int col = bn + wn + ni * 16 + l15;
        const float bv = bias[col];
        #pragma unroll
        for (int mi = 0; mi < 8; ++mi) {
            const int row0 = bm + wm + mi * 16 + lh * 4;
            const f32x4 v = acc[mi][ni];
            #pragma unroll
            for (int r = 0; r < 4; ++r)
                C[(size_t)(row0 + r) * N + col] = v[r] + bv;
        }
    }
#undef STAGE_A
#undef STAGE_B
}

extern "C" void kernel_launch(void* const* d_in, const int* in_sizes, int n_in,
                              void* d_out, int out_size, void* d_ws, size_t ws_size,
                              hipStream_t stream) {
    const float* x    = (const float*)d_in[0];
    const float* c0   = (const float*)d_in[1];
    const float* c1   = (const float*)d_in[2];
    const float* c2   = (const float*)d_in[3];
    const float* c3   = (const float*)d_in[4];
    const float* bias = (const float*)d_in[5];
    float* out = (float*)d_out;

    __bf16* xb = (__bf16*)d_ws;                    // 4096*1024 bf16 = 8.39 MB
    __bf16* wt = xb + (size_t)4096 * 1024;         // 4096*1024 bf16 = 8.39 MB

    prep<<<3072, 256, 0, stream>>>(x, xb, c0, c1, c2, c3, wt);
    tt_gemm<<<256, 512, 0, stream>>>(xb, wt, bias, out);
}

// Round 3
// 144.044 us; speedup vs baseline: 1.0332x; 1.0332x over previous
//
#include <hip/hip_runtime.h>
#include <hip/hip_bf16.h>
#include <cstdint>

// TT-linear: y[4096,4096] = x[4096,1024] @ W[1024,4096] + bias
// Kernel 1 (prep): fused x->bf16 convert + W^T reconstruction from TT cores (unchanged).
// Kernel 2 (tt_gemm): 256x256 tile, 8 waves, BK=32, 4-deep LDS ring.
// Round-3 fix: ONE barrier + one counted vmcnt per K-tile (was 4 barriers).
// R1/R2 showed the lockstep read-phase/MFMA-phase split serializes LDS reads
// (768 cyc) against MFMA (621 cyc) -> 21% MfmaUtil. Only two hazards exist:
//   S1: tile kt's global_load_lds landed before reads  (vmcnt(8) + barrier)
//   S2: tile kt's reads retired before STAGE(kt+4) issues (same barrier;
//       reads are consumed by MFMA lgkm deps before the wave reaches it)
// Everything else is free-running: compiler interleaves ds_read/MFMA with
// fine lgkmcnt(N), waves drift -> read latency hides under MFMA.

typedef __bf16 bf16x8 __attribute__((ext_vector_type(8)));
typedef float f32x4 __attribute__((ext_vector_type(4)));

__device__ __forceinline__ void g2lds16(const void* g, void* l) {
    __builtin_amdgcn_global_load_lds(
        (const __attribute__((address_space(1))) void*)g,
        (__attribute__((address_space(3))) void*)l,
        16, 0, 0);
}

// --------------------------------------------------------------------- prep
__global__ __launch_bounds__(256) void prep(
    const float* __restrict__ x, __bf16* __restrict__ xb,
    const float* __restrict__ c0, const float* __restrict__ c1,
    const float* __restrict__ c2, const float* __restrict__ c3,
    __bf16* __restrict__ wt) {
    const int b = blockIdx.x;
    const int t = threadIdx.x;
    if (b < 2048) {
        const int i = (b * 256 + t) * 8;
        float4 a0 = *(const float4*)(x + i);
        float4 a1 = *(const float4*)(x + i + 4);
        bf16x8 o;
        o[0] = (__bf16)a0.x; o[1] = (__bf16)a0.y; o[2] = (__bf16)a0.z; o[3] = (__bf16)a0.w;
        o[4] = (__bf16)a1.x; o[5] = (__bf16)a1.y; o[6] = (__bf16)a1.z; o[7] = (__bf16)a1.w;
        *(bf16x8*)(xb + i) = o;
        return;
    }
    __shared__ float t12[4][16];     // [wave][r2]
    __shared__ float t123[4][512];   // [wave][m3*8+n3][r3]
    __shared__ float c3s[512];       // [(r3*4+m4)*8+n4]
    #pragma unroll
    for (int i = t; i < 512; i += 256) c3s[i] = c3[i];
    const int s = t >> 6;
    const int lane = t & 63;
    const int g = (b - 2048) * 4 + s;
    const int m1 = g >> 9, n1 = (g >> 6) & 7, m2 = (g >> 3) & 7, n2 = g & 7;
    __syncthreads();
    if (lane < 16) {
        const int r2 = lane;
        float sum = 0.f;
        #pragma unroll
        for (int r1 = 0; r1 < 16; ++r1)
            sum += c0[(m1 * 8 + n1) * 16 + r1] * c1[((r1 * 8 + m2) * 8 + n2) * 16 + r2];
        t12[s][r2] = sum;
    }
    __syncthreads();
    #pragma unroll
    for (int idx = lane; idx < 512; idx += 64) {
        const int m3 = idx >> 7, n3 = (idx >> 4) & 7, r3 = idx & 15;
        float sum = 0.f;
        #pragma unroll
        for (int r2 = 0; r2 < 16; ++r2)
            sum += t12[s][r2] * c2[((r2 * 4 + m3) * 8 + n3) * 16 + r3];
        t123[s][(m3 * 8 + n3) * 16 + r3] = sum;
    }
    __syncthreads();
    const int n3 = lane >> 3, n4 = lane & 7;
    const int n = ((n1 * 8 + n2) * 8 + n3) * 8 + n4;
    const int kbase = (m1 * 8 + m2) * 16;
    float v[16];
    #pragma unroll
    for (int e = 0; e < 16; ++e) v[e] = 0.f;
    #pragma unroll
    for (int m3 = 0; m3 < 4; ++m3) {
        #pragma unroll
        for (int r3 = 0; r3 < 16; ++r3) {
            const float tv = t123[s][(m3 * 8 + n3) * 16 + r3];
            #pragma unroll
            for (int m4 = 0; m4 < 4; ++m4)
                v[m3 * 4 + m4] += tv * c3s[(r3 * 4 + m4) * 8 + n4];
        }
    }
    bf16x8 lo, hi;
    #pragma unroll
    for (int e = 0; e < 8; ++e) { lo[e] = (__bf16)v[e]; hi[e] = (__bf16)v[8 + e]; }
    *(bf16x8*)(wt + (size_t)n * 1024 + kbase)     = lo;
    *(bf16x8*)(wt + (size_t)n * 1024 + kbase + 8) = hi;
}

// -------------------------------------------------------------- GEMM + bias
// C[4096,4096] f32 = A[4096,1024] bf16 @ Bt[4096,1024]^T bf16 + bias
// 256x256 block tile, BK=32, 8 waves (2M x 4N), per-wave 128x64 output.
// LDS: 4-deep ring x (A 16KB + B 16KB) = 128 KB; tile kt lives in slot kt&3,
// staged at tile kt-3. vmcnt(8) at end of tile kt: 12 loads outstanding
// (kt+1,kt+2,kt+3), waits oldest 4 => kt+1 fully in LDS.
// Swizzle: 64-B rows, 4 x 16B chunks; physical chunk pc holds logical
// pc^((r>>1)&3); staging pre-swizzles the GLOBAL source so global_load_lds
// destinations stay linear; fragment ds_read_b128 then lands 2 lanes/bank.

#define SCHED_FENCE() __builtin_amdgcn_sched_barrier(0)

__global__ __launch_bounds__(512, 2) void tt_gemm(
    const __bf16* __restrict__ A, const __bf16* __restrict__ B,
    const float* __restrict__ bias, float* __restrict__ C) {
    constexpr int K = 1024, N = 4096;
    constexpr int NT = K / 32;              // 32 k-tiles
    __shared__ __bf16 sA[4][256 * 32];      // 4 x 16 KB
    __shared__ __bf16 sB[4][256 * 32];      // 4 x 16 KB
    const int t = threadIdx.x;
    const int lane = t & 63;
    const int wave = t >> 6;                // 0..7
    const int wm = (wave >> 2) * 128;       // 0 / 128
    const int wn = (wave & 3) * 64;         // 0..192
    const int l15 = lane & 15, lh = lane >> 4;
    const int coff = (lh ^ ((l15 >> 1) & 3)) * 16;  // swizzled byte offset in 64-B row

    // XCD-aware mapping: each XCD owns an 8m x 4n rectangle of tiles (bijective)
    const int xcd = blockIdx.x & 7;
    const int lid = blockIdx.x >> 3;        // 0..31
    const int bm = ((xcd >> 2) * 8 + (lid & 7)) * 256;
    const int bn = ((xcd & 3) * 4 + (lid >> 3)) * 256;

    // staging: thread owns chunks c = t and t+512 of each 1024-chunk tile
    const int c0i = t, c1i = t + 512;
    const int r0 = c0i >> 2, r1 = c1i >> 2;             // tile row 0..255
    const int lc0 = (c0i & 3) ^ ((r0 >> 1) & 3);        // logical (global) chunk
    const int lc1 = (c1i & 3) ^ ((r1 >> 1) & 3);
    const __bf16* a0p = A + (size_t)(bm + r0) * K + lc0 * 8;
    const __bf16* a1p = A + (size_t)(bm + r1) * K + lc1 * 8;
    const __bf16* b0p = B + (size_t)(bn + r0) * K + lc0 * 8;
    const __bf16* b1p = B + (size_t)(bn + r1) * K + lc1 * 8;

#define STAGE_A(kt) do { \
    g2lds16(a0p + (kt) * 32, (char*)sA[(kt) & 3] + c0i * 16); \
    g2lds16(a1p + (kt) * 32, (char*)sA[(kt) & 3] + c1i * 16); } while (0)
#define STAGE_B(kt) do { \
    g2lds16(b0p + (kt) * 32, (char*)sB[(kt) & 3] + c0i * 16); \
    g2lds16(b1p + (kt) * 32, (char*)sB[(kt) & 3] + c1i * 16); } while (0)

    // one K-tile of compute: 12 frag reads + 32 MFMA, no internal barriers.
    // Compiler owns the ds_read->MFMA ordering via dataflow (fine lgkmcnt(N)).
#define TILE_COMPUTE(kt) do {                                                  \
    const char* la = (const char*)sA[(kt) & 3];                                \
    const char* lb = (const char*)sB[(kt) & 3];                                \
    bf16x8 af[8], bfr[4];                                                      \
    _Pragma("unroll")                                                          \
    for (int mi = 0; mi < 8; ++mi)                                             \
        af[mi] = *(const bf16x8*)(la + (wm + mi * 16 + l15) * 64 + coff);      \
    _Pragma("unroll")                                                          \
    for (int ni = 0; ni < 4; ++ni)                                             \
        bfr[ni] = *(const bf16x8*)(lb + (wn + ni * 16 + l15) * 64 + coff);     \
    __builtin_amdgcn_s_setprio(1);                                             \
    _Pragma("unroll")                                                          \
    for (int mi = 0; mi < 8; ++mi)                                             \
        _Pragma("unroll")                                                      \
        for (int ni = 0; ni < 4; ++ni)                                         \
            acc[mi][ni] = __builtin_amdgcn_mfma_f32_16x16x32_bf16(             \
                af[mi], bfr[ni], acc[mi][ni], 0, 0, 0);                        \
    __builtin_amdgcn_s_setprio(0);                                             \
} while (0)

    f32x4 acc[8][4] = {};

    // prologue: stage tiles 0,1,2 (12 loads); wait until tile 0 (oldest 4) done
    STAGE_A(0); STAGE_B(0);
    STAGE_A(1); STAGE_B(1);
    STAGE_A(2); STAGE_B(2);
    SCHED_FENCE();
    asm volatile("s_waitcnt vmcnt(8)");
    SCHED_FENCE();
    __builtin_amdgcn_s_barrier();
    SCHED_FENCE();

    #pragma unroll 1
    for (int kt = 0; kt < NT - 3; ++kt) {
        STAGE_A(kt + 3); STAGE_B(kt + 3);   // issue-early: hides HBM/L2 latency
        TILE_COMPUTE(kt);
        SCHED_FENCE();                       // pin all tile work before the sync
        asm volatile("s_waitcnt vmcnt(8)");  // my loads for kt+1 landed
        __builtin_amdgcn_s_barrier();        // collective: kt+1 readable (S1),
        SCHED_FENCE();                       // reads of kt done grid-wide (S2)
    }

    // tail tiles NT-3..NT-1: no staging left; drain vmcnt 4 -> 0
    TILE_COMPUTE(NT - 3);
    SCHED_FENCE();
    asm volatile("s_waitcnt vmcnt(4)");
    __builtin_amdgcn_s_barrier();
    SCHED_FENCE();
    TILE_COMPUTE(NT - 2);
    SCHED_FENCE();
    asm volatile("s_waitcnt vmcnt(0)");
    __builtin_amdgcn_s_barrier();
    SCHED_FENCE();
    TILE_COMPUTE(NT - 1);

    // epilogue: C/D layout col=lane&15, row=(lane>>4)*4+reg (m89-verified).
    // ni-inner store order: each wave emits 4x64B = 256B contiguous per row
    // (R2 counters showed WRITE_SIZE 92MB vs 67MB ideal from scattered 64B segs)
    float bv[4];
    #pragma unroll
    for (int ni = 0; ni < 4; ++ni) bv[ni] = bias[bn + wn + ni * 16 + l15];
    #pragma unroll
    for (int mi = 0; mi < 8; ++mi) {
        #pragma unroll
        for (int r = 0; r < 4; ++r) {
            const int row = bm + wm + mi * 16 + lh * 4 + r;
            float* crow = C + (size_t)row * N + bn + wn + l15;
            #pragma unroll
            for (int ni = 0; ni < 4; ++ni)
                crow[ni * 16] = acc[mi][ni][r] + bv[ni];
        }
    }
#undef STAGE_A
#undef STAGE_B
#undef TILE_COMPUTE
}

extern "C" void kernel_launch(void* const* d_in, const int* in_sizes, int n_in,
                              void* d_out, int out_size, void* d_ws, size_t ws_size,
                              hipStream_t stream) {
    const float* x    = (const float*)d_in[0];
    const float* c0   = (const float*)d_in[1];
    const float* c1   = (const float*)d_in[2];
    const float* c2   = (const float*)d_in[3];
    const float* c3   = (const float*)d_in[4];
    const float* bias = (const float*)d_in[5];
    float* out = (float*)d_out;

    __bf16* xb = (__bf16*)d_ws;                    // 4096*1024 bf16 = 8.39 MB
    __bf16* wt = xb + (size_t)4096 * 1024;         // 4096*1024 bf16 = 8.39 MB

    prep<<<3072, 256, 0, stream>>>(x, xb, c0, c1, c2, c3, wt);
    tt_gemm<<<256, 512, 0, stream>>>(xb, wt, bias, out);
}

// Round 4
// 139.771 us; speedup vs baseline: 1.0647x; 1.0306x over previous
//
#include <hip/hip_runtime.h>
#include <hip/hip_bf16.h>
#include <cstdint>

// TT-linear: y[4096,4096] = x[4096,1024] @ W[1024,4096] + bias
// Kernel 1 (prep): fused x->bf16 convert + W^T reconstruction from TT cores (unchanged).
// Kernel 2 (tt_gemm): faithful 8-phase-template port (m201/m248 verified structure):
//   256x256 tile, BK=64, 8 waves (2Mx4N, wave=128x64), LDS 2-deep dbuf with
//   K-SPLIT half-tiles (ks-halves) so depth-2 staging is race-free:
//     per K-tile, 4 phases {ds_read 4-8 x b128; stage 1 half (2 loads); barrier;
//     setprio(1); 16 MFMA; setprio(0); [counted vmcnt]; barrier}
//   ks0 LDS regions die after P1 -> staging kt+2's ks0 at P2/P3 into the
//   current slot cannot race. vmcnt(8) after P1/P3 only (never 0 mid-loop).

typedef __bf16 bf16x8 __attribute__((ext_vector_type(8)));
typedef float f32x4 __attribute__((ext_vector_type(4)));

__device__ __forceinline__ void g2lds16(const void* g, void* l) {
    __builtin_amdgcn_global_load_lds(
        (const __attribute__((address_space(1))) void*)g,
        (__attribute__((address_space(3))) void*)l,
        16, 0, 0);
}

// --------------------------------------------------------------------- prep
__global__ __launch_bounds__(256) void prep(
    const float* __restrict__ x, __bf16* __restrict__ xb,
    const float* __restrict__ c0, const float* __restrict__ c1,
    const float* __restrict__ c2, const float* __restrict__ c3,
    __bf16* __restrict__ wt) {
    const int b = blockIdx.x;
    const int t = threadIdx.x;
    if (b < 2048) {
        const int i = (b * 256 + t) * 8;
        float4 a0 = *(const float4*)(x + i);
        float4 a1 = *(const float4*)(x + i + 4);
        bf16x8 o;
        o[0] = (__bf16)a0.x; o[1] = (__bf16)a0.y; o[2] = (__bf16)a0.z; o[3] = (__bf16)a0.w;
        o[4] = (__bf16)a1.x; o[5] = (__bf16)a1.y; o[6] = (__bf16)a1.z; o[7] = (__bf16)a1.w;
        *(bf16x8*)(xb + i) = o;
        return;
    }
    __shared__ float t12[4][16];     // [wave][r2]
    __shared__ float t123[4][512];   // [wave][m3*8+n3][r3]
    __shared__ float c3s[512];       // [(r3*4+m4)*8+n4]
    #pragma unroll
    for (int i = t; i < 512; i += 256) c3s[i] = c3[i];
    const int s = t >> 6;
    const int lane = t & 63;
    const int g = (b - 2048) * 4 + s;
    const int m1 = g >> 9, n1 = (g >> 6) & 7, m2 = (g >> 3) & 7, n2 = g & 7;
    __syncthreads();
    if (lane < 16) {
        const int r2 = lane;
        float sum = 0.f;
        #pragma unroll
        for (int r1 = 0; r1 < 16; ++r1)
            sum += c0[(m1 * 8 + n1) * 16 + r1] * c1[((r1 * 8 + m2) * 8 + n2) * 16 + r2];
        t12[s][r2] = sum;
    }
    __syncthreads();
    #pragma unroll
    for (int idx = lane; idx < 512; idx += 64) {
        const int m3 = idx >> 7, n3 = (idx >> 4) & 7, r3 = idx & 15;
        float sum = 0.f;
        #pragma unroll
        for (int r2 = 0; r2 < 16; ++r2)
            sum += t12[s][r2] * c2[((r2 * 4 + m3) * 8 + n3) * 16 + r3];
        t123[s][(m3 * 8 + n3) * 16 + r3] = sum;
    }
    __syncthreads();
    const int n3 = lane >> 3, n4 = lane & 7;
    const int n = ((n1 * 8 + n2) * 8 + n3) * 8 + n4;
    const int kbase = (m1 * 8 + m2) * 16;
    float v[16];
    #pragma unroll
    for (int e = 0; e < 16; ++e) v[e] = 0.f;
    #pragma unroll
    for (int m3 = 0; m3 < 4; ++m3) {
        #pragma unroll
        for (int r3 = 0; r3 < 16; ++r3) {
            const float tv = t123[s][(m3 * 8 + n3) * 16 + r3];
            #pragma unroll
            for (int m4 = 0; m4 < 4; ++m4)
                v[m3 * 4 + m4] += tv * c3s[(r3 * 4 + m4) * 8 + n4];
        }
    }
    bf16x8 lo, hi;
    #pragma unroll
    for (int e = 0; e < 8; ++e) { lo[e] = (__bf16)v[e]; hi[e] = (__bf16)v[8 + e]; }
    *(bf16x8*)(wt + (size_t)n * 1024 + kbase)     = lo;
    *(bf16x8*)(wt + (size_t)n * 1024 + kbase + 8) = hi;
}

// -------------------------------------------------------------- GEMM + bias
// C[4096,4096] f32 = A[4096,1024] bf16 @ Bt[4096,1024]^T bf16 + bias
// Geometry: BM=BN=256, BK=64 (16 K-tiles), 8 waves 2Mx4N (wave out 128x64),
// 512 threads. LDS sA/sB[2 slots][2 ks-halves][256 rows x 32 cols] = 128 KB.
// Swizzle (64-B ks-half rows, 4 x 16B chunks): phys chunk = logical ^ (row&3).
// Fragment read: lane(l15,lh) chunk = lh ^ (l15&3) -> 8 lanes per 4-bank group
// = conflict-free. Staging pre-swizzles the GLOBAL source (rule 21).
// Stage stream (1 half/phase): kt's P0: A-ks1(kt+1), P1: B-ks1(kt+1),
//                              P2: A-ks0(kt+2), P3: B-ks0(kt+2).
// vmcnt(8) after P1 (gates ks1 reads at P2) and after P3 (gates kt+1's P0).

#define SCHED() __builtin_amdgcn_sched_barrier(0)
#define BAR()  do { SCHED(); __builtin_amdgcn_s_barrier(); SCHED(); } while (0)
#define WAITVM(n) do { SCHED(); asm volatile("s_waitcnt vmcnt(" #n ")"); SCHED(); } while (0)

__global__ __launch_bounds__(512, 2) void tt_gemm(
    const __bf16* __restrict__ A, const __bf16* __restrict__ B,
    const float* __restrict__ bias, float* __restrict__ C) {
    constexpr int K = 1024, N = 4096;
    constexpr int NKT = 16;                  // K-tiles of 64
    __shared__ __bf16 sA[2][2][256 * 32];    // [slot][ks][16 KB]
    __shared__ __bf16 sB[2][2][256 * 32];
    const int t = threadIdx.x;
    const int lane = t & 63;
    const int wave = t >> 6;                 // 0..7
    const int wm = (wave >> 2) * 128;        // 0 / 128   (M range of wave)
    const int wn = (wave & 3) * 64;          // 0..192    (N range of wave)
    const int l15 = lane & 15, lh = lane >> 4;
    const int cOff = ((lh ^ (l15 & 3)) << 4);  // swizzled 16B chunk in 64-B row

    // XCD-aware mapping: each XCD owns a 2m x 4n rectangle of 256-tiles
    const int xcd = blockIdx.x & 7;
    const int lid = blockIdx.x >> 3;         // 0..31
    const int bm = ((xcd >> 2) * 8 + (lid & 7)) * 256;
    const int bn = ((xcd & 3) * 4 + (lid >> 3)) * 256;

    // staging: 16-KB ks-half = 1024 chunks of 16B; thread owns c = t, t+512
    const int c0i = t, c1i = t + 512;
    const int r0 = c0i >> 2, r1 = c1i >> 2;              // row in tile 0..255
    const int lc0 = (c0i & 3) ^ (r0 & 3);                // logical chunk (global)
    const int lc1 = (c1i & 3) ^ (r1 & 3);
    const __bf16* a0p = A + (size_t)(bm + r0) * K + lc0 * 8;
    const __bf16* a1p = A + (size_t)(bm + r1) * K + lc1 * 8;
    const __bf16* b0p = B + (size_t)(bn + r0) * K + lc0 * 8;
    const __bf16* b1p = B + (size_t)(bn + r1) * K + lc1 * 8;

#define ST_A(kt, ks) do { \
    g2lds16(a0p + (size_t)(kt) * 64 + (ks) * 32, (char*)&sA[(kt) & 1][ks][0] + c0i * 16); \
    g2lds16(a1p + (size_t)(kt) * 64 + (ks) * 32, (char*)&sA[(kt) & 1][ks][0] + c1i * 16); } while (0)
#define ST_B(kt, ks) do { \
    g2lds16(b0p + (size_t)(kt) * 64 + (ks) * 32, (char*)&sB[(kt) & 1][ks][0] + c0i * 16); \
    g2lds16(b1p + (size_t)(kt) * 64 + (ks) * 32, (char*)&sB[(kt) & 1][ks][0] + c1i * 16); } while (0)
#define LDA(dst, fi, ks) dst = *(const bf16x8*)((const char*)&sA[slot][ks][0] + (wm + (fi) * 16 + l15) * 64 + cOff)
#define LDB(dst, ni, ks) dst = *(const bf16x8*)((const char*)&sB[slot][ks][0] + (wn + (ni) * 16 + l15) * 64 + cOff)
#define MFMA16(base, afr) do { \
    __builtin_amdgcn_s_setprio(1); \
    _Pragma("unroll") \
    for (int mi = 0; mi < 4; ++mi) \
        _Pragma("unroll") \
        for (int ni = 0; ni < 4; ++ni) \
            acc[(base) + mi][ni] = __builtin_amdgcn_mfma_f32_16x16x32_bf16( \
                afr[mi], bb[ni], acc[(base) + mi][ni], 0, 0, 0); \
    __builtin_amdgcn_s_setprio(0); } while (0)

    f32x4 acc[8][4] = {};

    // prologue: A0(0),B0(0),A1(0),B1(0),A0(1),B0(1) = 12 loads; oldest 4 = kt0 ks0
    ST_A(0, 0); ST_B(0, 0);
    ST_A(0, 1); ST_B(0, 1);
    ST_A(1, 0); ST_B(1, 0);
    WAITVM(8);
    BAR();

    #pragma unroll 1
    for (int kt = 0; kt < NKT; ++kt) {
        const int slot = kt & 1;
        bf16x8 aL[4], aH[4], bb[4];
        // ---- P0: frags (m-low, ks0) + all B ks0; stage A-ks1(kt+1)
        #pragma unroll
        for (int mi = 0; mi < 4; ++mi) LDA(aL[mi], mi, 0);
        #pragma unroll
        for (int ni = 0; ni < 4; ++ni) LDB(bb[ni], ni, 0);
        if (kt < NKT - 1) ST_A(kt + 1, 1);
        BAR();
        MFMA16(0, aL);
        BAR();
        // ---- P1: frags (m-high, ks0); stage B-ks1(kt+1); vmcnt gates ks1 reads
        #pragma unroll
        for (int mi = 0; mi < 4; ++mi) LDA(aH[mi], 4 + mi, 0);
        if (kt < NKT - 1) ST_B(kt + 1, 1);
        BAR();
        MFMA16(4, aH);
        if (kt < NKT - 1) { WAITVM(8); } else { WAITVM(0); }
        BAR();
        // ---- P2: frags (m-low, ks1) + all B ks1; stage A-ks0(kt+2)
        #pragma unroll
        for (int mi = 0; mi < 4; ++mi) LDA(aL[mi], mi, 1);
        #pragma unroll
        for (int ni = 0; ni < 4; ++ni) LDB(bb[ni], ni, 1);
        if (kt < NKT - 2) ST_A(kt + 2, 0);
        BAR();
        MFMA16(0, aL);
        BAR();
        // ---- P3: frags (m-high, ks1); stage B-ks0(kt+2); vmcnt gates next P0
        #pragma unroll
        for (int mi = 0; mi < 4; ++mi) LDA(aH[mi], 4 + mi, 1);
        if (kt < NKT - 2) ST_B(kt + 2, 0);
        BAR();
        MFMA16(4, aH);
        if (kt < NKT - 2)      { WAITVM(8); }
        else if (kt == NKT - 2) { WAITVM(4); }
        BAR();
    }

    // epilogue: C/D layout col=lane&15, row=(lane>>4)*4+reg (m89-verified);
    // ni-inner store order -> 256B contiguous per wave-row (WRITE_SIZE ~ideal)
    float bv[4];
    #pragma unroll
    for (int ni = 0; ni < 4; ++ni) bv[ni] = bias[bn + wn + ni * 16 + l15];
    #pragma unroll
    for (int mi = 0; mi < 8; ++mi) {
        #pragma unroll
        for (int r = 0; r < 4; ++r) {
            const int row = bm + wm + mi * 16 + lh * 4 + r;
            float* crow = C + (size_t)row * N + bn + wn + l15;
            #pragma unroll
            for (int ni = 0; ni < 4; ++ni)
                crow[ni * 16] = acc[mi][ni][r] + bv[ni];
        }
    }
#undef ST_A
#undef ST_B
#undef LDA
#undef LDB
#undef MFMA16
}

extern "C" void kernel_launch(void* const* d_in, const int* in_sizes, int n_in,
                              void* d_out, int out_size, void* d_ws, size_t ws_size,
                              hipStream_t stream) {
    const float* x    = (const float*)d_in[0];
    const float* c0   = (const float*)d_in[1];
    const float* c1   = (const float*)d_in[2];
    const float* c2   = (const float*)d_in[3];
    const float* c3   = (const float*)d_in[4];
    const float* bias = (const float*)d_in[5];
    float* out = (float*)d_out;

    __bf16* xb = (__bf16*)d_ws;                    // 4096*1024 bf16 = 8.39 MB
    __bf16* wt = xb + (size_t)4096 * 1024;         // 4096*1024 bf16 = 8.39 MB

    prep<<<3072, 256, 0, stream>>>(x, xb, c0, c1, c2, c3, wt);
    tt_gemm<<<256, 512, 0, stream>>>(xb, wt, bias, out);
}

// Round 5
// 135.900 us; speedup vs baseline: 1.0951x; 1.0285x over previous
//
#include <hip/hip_runtime.h>
#include <hip/hip_bf16.h>
#include <cstdint>

// TT-linear: y[4096,4096] = x[4096,1024] @ W[1024,4096] + bias
// Kernel 1 (prep): fused x->bf16 convert + W^T reconstruction from TT cores (unchanged).
// Kernel 2 (tt_gemm): 8-phase template (m201/m248 structure), 256x256 tile, BK=64,
//   8 waves (2Mx4N, wave=128x64), LDS 2-deep dbuf with K-split half-tiles.
// Round-5 fix: revert swizzle to the R3 involution ((x>>1)&3). R4's (x&3) variant
// put lanes {0,4},{1,5},{2,6},{3,7} of each 8-lane LDS service batch on the same
// 16B bank group -> 3.1M conflict cycles (12.3k cyc/CU ~ 10% of kernel). The
// (x>>1)&3 pattern gives all-distinct groups per batch (R3 measured 0 conflicts).

typedef __bf16 bf16x8 __attribute__((ext_vector_type(8)));
typedef float f32x4 __attribute__((ext_vector_type(4)));

__device__ __forceinline__ void g2lds16(const void* g, void* l) {
    __builtin_amdgcn_global_load_lds(
        (const __attribute__((address_space(1))) void*)g,
        (__attribute__((address_space(3))) void*)l,
        16, 0, 0);
}

// --------------------------------------------------------------------- prep
__global__ __launch_bounds__(256) void prep(
    const float* __restrict__ x, __bf16* __restrict__ xb,
    const float* __restrict__ c0, const float* __restrict__ c1,
    const float* __restrict__ c2, const float* __restrict__ c3,
    __bf16* __restrict__ wt) {
    const int b = blockIdx.x;
    const int t = threadIdx.x;
    if (b < 2048) {
        const int i = (b * 256 + t) * 8;
        float4 a0 = *(const float4*)(x + i);
        float4 a1 = *(const float4*)(x + i + 4);
        bf16x8 o;
        o[0] = (__bf16)a0.x; o[1] = (__bf16)a0.y; o[2] = (__bf16)a0.z; o[3] = (__bf16)a0.w;
        o[4] = (__bf16)a1.x; o[5] = (__bf16)a1.y; o[6] = (__bf16)a1.z; o[7] = (__bf16)a1.w;
        *(bf16x8*)(xb + i) = o;
        return;
    }
    __shared__ float t12[4][16];     // [wave][r2]
    __shared__ float t123[4][512];   // [wave][m3*8+n3][r3]
    __shared__ float c3s[512];       // [(r3*4+m4)*8+n4]
    #pragma unroll
    for (int i = t; i < 512; i += 256) c3s[i] = c3[i];
    const int s = t >> 6;
    const int lane = t & 63;
    const int g = (b - 2048) * 4 + s;
    const int m1 = g >> 9, n1 = (g >> 6) & 7, m2 = (g >> 3) & 7, n2 = g & 7;
    __syncthreads();
    if (lane < 16) {
        const int r2 = lane;
        float sum = 0.f;
        #pragma unroll
        for (int r1 = 0; r1 < 16; ++r1)
            sum += c0[(m1 * 8 + n1) * 16 + r1] * c1[((r1 * 8 + m2) * 8 + n2) * 16 + r2];
        t12[s][r2] = sum;
    }
    __syncthreads();
    #pragma unroll
    for (int idx = lane; idx < 512; idx += 64) {
        const int m3 = idx >> 7, n3 = (idx >> 4) & 7, r3 = idx & 15;
        float sum = 0.f;
        #pragma unroll
        for (int r2 = 0; r2 < 16; ++r2)
            sum += t12[s][r2] * c2[((r2 * 4 + m3) * 8 + n3) * 16 + r3];
        t123[s][(m3 * 8 + n3) * 16 + r3] = sum;
    }
    __syncthreads();
    const int n3 = lane >> 3, n4 = lane & 7;
    const int n = ((n1 * 8 + n2) * 8 + n3) * 8 + n4;
    const int kbase = (m1 * 8 + m2) * 16;
    float v[16];
    #pragma unroll
    for (int e = 0; e < 16; ++e) v[e] = 0.f;
    #pragma unroll
    for (int m3 = 0; m3 < 4; ++m3) {
        #pragma unroll
        for (int r3 = 0; r3 < 16; ++r3) {
            const float tv = t123[s][(m3 * 8 + n3) * 16 + r3];
            #pragma unroll
            for (int m4 = 0; m4 < 4; ++m4)
                v[m3 * 4 + m4] += tv * c3s[(r3 * 4 + m4) * 8 + n4];
        }
    }
    bf16x8 lo, hi;
    #pragma unroll
    for (int e = 0; e < 8; ++e) { lo[e] = (__bf16)v[e]; hi[e] = (__bf16)v[8 + e]; }
    *(bf16x8*)(wt + (size_t)n * 1024 + kbase)     = lo;
    *(bf16x8*)(wt + (size_t)n * 1024 + kbase + 8) = hi;
}

// -------------------------------------------------------------- GEMM + bias
// C[4096,4096] f32 = A[4096,1024] bf16 @ Bt[4096,1024]^T bf16 + bias
// Geometry: BM=BN=256, BK=64 (16 K-tiles), 8 waves 2Mx4N (wave out 128x64),
// 512 threads. LDS sA/sB[2 slots][2 ks-halves][256 rows x 32 cols] = 128 KB.
// Swizzle (64-B ks-half rows, 4 x 16B chunks): phys chunk = logical ^ ((row>>1)&3).
// Fragment read chunk = lh ^ ((l15>>1)&3): every 8-lane service batch hits 8
// distinct 16B bank groups (verified 0 conflicts, R3). Staging pre-swizzles
// the GLOBAL source so global_load_lds destinations stay linear (rule 21).
// Stage stream (1 half/phase): kt's P0: A-ks1(kt+1), P1: B-ks1(kt+1),
//                              P2: A-ks0(kt+2), P3: B-ks0(kt+2).
// vmcnt(8) after P1 (gates ks1 reads at P2) and after P3 (gates kt+1's P0).

#define SCHED() __builtin_amdgcn_sched_barrier(0)
#define BAR()  do { SCHED(); __builtin_amdgcn_s_barrier(); SCHED(); } while (0)
#define WAITVM(n) do { SCHED(); asm volatile("s_waitcnt vmcnt(" #n ")"); SCHED(); } while (0)

__global__ __launch_bounds__(512, 2) void tt_gemm(
    const __bf16* __restrict__ A, const __bf16* __restrict__ B,
    const float* __restrict__ bias, float* __restrict__ C) {
    constexpr int K = 1024, N = 4096;
    constexpr int NKT = 16;                  // K-tiles of 64
    __shared__ __bf16 sA[2][2][256 * 32];    // [slot][ks][16 KB]
    __shared__ __bf16 sB[2][2][256 * 32];
    const int t = threadIdx.x;
    const int lane = t & 63;
    const int wave = t >> 6;                 // 0..7
    const int wm = (wave >> 2) * 128;        // 0 / 128   (M range of wave)
    const int wn = (wave & 3) * 64;          // 0..192    (N range of wave)
    const int l15 = lane & 15, lh = lane >> 4;
    const int cOff = ((lh ^ ((l15 >> 1) & 3)) << 4);  // swizzled 16B chunk in 64-B row

    // XCD-aware mapping: each XCD owns an 8m x 4n rectangle of 256-tiles
    const int xcd = blockIdx.x & 7;
    const int lid = blockIdx.x >> 3;         // 0..31
    const int bm = ((xcd >> 2) * 8 + (lid & 7)) * 256;
    const int bn = ((xcd & 3) * 4 + (lid >> 3)) * 256;

    // staging: 16-KB ks-half = 1024 chunks of 16B; thread owns c = t, t+512
    const int c0i = t, c1i = t + 512;
    const int r0 = c0i >> 2, r1 = c1i >> 2;              // row in tile 0..255
    const int lc0 = (c0i & 3) ^ ((r0 >> 1) & 3);         // logical chunk (global)
    const int lc1 = (c1i & 3) ^ ((r1 >> 1) & 3);
    const __bf16* a0p = A + (size_t)(bm + r0) * K + lc0 * 8;
    const __bf16* a1p = A + (size_t)(bm + r1) * K + lc1 * 8;
    const __bf16* b0p = B + (size_t)(bn + r0) * K + lc0 * 8;
    const __bf16* b1p = B + (size_t)(bn + r1) * K + lc1 * 8;

#define ST_A(kt, ks) do { \
    g2lds16(a0p + (size_t)(kt) * 64 + (ks) * 32, (char*)&sA[(kt) & 1][ks][0] + c0i * 16); \
    g2lds16(a1p + (size_t)(kt) * 64 + (ks) * 32, (char*)&sA[(kt) & 1][ks][0] + c1i * 16); } while (0)
#define ST_B(kt, ks) do { \
    g2lds16(b0p + (size_t)(kt) * 64 + (ks) * 32, (char*)&sB[(kt) & 1][ks][0] + c0i * 16); \
    g2lds16(b1p + (size_t)(kt) * 64 + (ks) * 32, (char*)&sB[(kt) & 1][ks][0] + c1i * 16); } while (0)
#define LDA(dst, fi, ks) dst = *(const bf16x8*)((const char*)&sA[slot][ks][0] + (wm + (fi) * 16 + l15) * 64 + cOff)
#define LDB(dst, ni, ks) dst = *(const bf16x8*)((const char*)&sB[slot][ks][0] + (wn + (ni) * 16 + l15) * 64 + cOff)
#define MFMA16(base, afr) do { \
    __builtin_amdgcn_s_setprio(1); \
    _Pragma("unroll") \
    for (int mi = 0; mi < 4; ++mi) \
        _Pragma("unroll") \
        for (int ni = 0; ni < 4; ++ni) \
            acc[(base) + mi][ni] = __builtin_amdgcn_mfma_f32_16x16x32_bf16( \
                afr[mi], bb[ni], acc[(base) + mi][ni], 0, 0, 0); \
    __builtin_amdgcn_s_setprio(0); } while (0)

    f32x4 acc[8][4] = {};

    // prologue: A0(0),B0(0),A0(1),B0(1),A1(0),B1(0) = 12 loads; oldest 4 = kt0 ks0
    ST_A(0, 0); ST_B(0, 0);
    ST_A(0, 1); ST_B(0, 1);
    ST_A(1, 0); ST_B(1, 0);
    WAITVM(8);
    BAR();

    #pragma unroll 1
    for (int kt = 0; kt < NKT; ++kt) {
        const int slot = kt & 1;
        bf16x8 aL[4], aH[4], bb[4];
        // ---- P0: frags (m-low, ks0) + all B ks0; stage A-ks1(kt+1)
        #pragma unroll
        for (int mi = 0; mi < 4; ++mi) LDA(aL[mi], mi, 0);
        #pragma unroll
        for (int ni = 0; ni < 4; ++ni) LDB(bb[ni], ni, 0);
        if (kt < NKT - 1) ST_A(kt + 1, 1);
        BAR();
        MFMA16(0, aL);
        BAR();
        // ---- P1: frags (m-high, ks0); stage B-ks1(kt+1); vmcnt gates ks1 reads
        #pragma unroll
        for (int mi = 0; mi < 4; ++mi) LDA(aH[mi], 4 + mi, 0);
        if (kt < NKT - 1) ST_B(kt + 1, 1);
        BAR();
        MFMA16(4, aH);
        if (kt < NKT - 1) { WAITVM(8); } else { WAITVM(0); }
        BAR();
        // ---- P2: frags (m-low, ks1) + all B ks1; stage A-ks0(kt+2)
        #pragma unroll
        for (int mi = 0; mi < 4; ++mi) LDA(aL[mi], mi, 1);
        #pragma unroll
        for (int ni = 0; ni < 4; ++ni) LDB(bb[ni], ni, 1);
        if (kt < NKT - 2) ST_A(kt + 2, 0);
        BAR();
        MFMA16(0, aL);
        BAR();
        // ---- P3: frags (m-high, ks1); stage B-ks0(kt+2); vmcnt gates next P0
        #pragma unroll
        for (int mi = 0; mi < 4; ++mi) LDA(aH[mi], 4 + mi, 1);
        if (kt < NKT - 2) ST_B(kt + 2, 0);
        BAR();
        MFMA16(4, aH);
        if (kt < NKT - 2)      { WAITVM(8); }
        else if (kt == NKT - 2) { WAITVM(4); }
        BAR();
    }

    // epilogue: C/D layout col=lane&15, row=(lane>>4)*4+reg (m89-verified);
    // ni-inner store order -> 256B contiguous per wave-row (WRITE_SIZE ~ideal)
    float bv[4];
    #pragma unroll
    for (int ni = 0; ni < 4; ++ni) bv[ni] = bias[bn + wn + ni * 16 + l15];
    #pragma unroll
    for (int mi = 0; mi < 8; ++mi) {
        #pragma unroll
        for (int r = 0; r < 4; ++r) {
            const int row = bm + wm + mi * 16 + lh * 4 + r;
            float* crow = C + (size_t)row * N + bn + wn + l15;
            #pragma unroll
            for (int ni = 0; ni < 4; ++ni)
                crow[ni * 16] = acc[mi][ni][r] + bv[ni];
        }
    }
#undef ST_A
#undef ST_B
#undef LDA
#undef LDB
#undef MFMA16
}

extern "C" void kernel_launch(void* const* d_in, const int* in_sizes, int n_in,
                              void* d_out, int out_size, void* d_ws, size_t ws_size,
                              hipStream_t stream) {
    const float* x    = (const float*)d_in[0];
    const float* c0   = (const float*)d_in[1];
    const float* c1   = (const float*)d_in[2];
    const float* c2   = (const float*)d_in[3];
    const float* c3   = (const float*)d_in[4];
    const float* bias = (const float*)d_in[5];
    float* out = (float*)d_out;

    __bf16* xb = (__bf16*)d_ws;                    // 4096*1024 bf16 = 8.39 MB
    __bf16* wt = xb + (size_t)4096 * 1024;         // 4096*1024 bf16 = 8.39 MB

    prep<<<3072, 256, 0, stream>>>(x, xb, c0, c1, c2, c3, wt);
    tt_gemm<<<256, 512, 0, stream>>>(xb, wt, bias, out);
}